// Round 2
// baseline (966.499 us; speedup 1.0000x reference)
//
#include <hip/hip_runtime.h>

#define TT 512
#define BB 4096

__device__ __forceinline__ float fast_rcp(float x) { return __builtin_amdgcn_rcpf(x); }
__device__ __forceinline__ float sigmoid_f(float x) { return fast_rcp(1.0f + __expf(-x)); }
__device__ __forceinline__ float tanh_f(float x) {
    return fmaf(2.0f, fast_rcp(1.0f + __expf(-2.0f * x)), -1.0f);
}

// 64 lanes (one full wave) per batch element:
//   lane = (o in 0..15: output unit) + 16*(half in 0..1: K-half) + 32*(s in 0..1: x-side / h-side)
// Block = 256 threads = 4 batch elements (4 waves, no cross-wave sharing, no __syncthreads).
// Grid = 4096/4 = 1024 blocks -> 4096 waves -> 4 waves/SIMD.
__global__ __launch_bounds__(256, 4)
void gru_fused_kernel(const float* __restrict__ x, const float* __restrict__ h0,
                      const float* __restrict__ W_emb, const float* __restrict__ b_emb,
                      const float* __restrict__ W_out, const float* __restrict__ b_out,
                      const float* __restrict__ Wih0, const float* __restrict__ Whh0,
                      const float* __restrict__ bih0, const float* __restrict__ bhh0,
                      const float* __restrict__ Wih1, const float* __restrict__ Whh1,
                      const float* __restrict__ bih1, const float* __restrict__ bhh1,
                      const float* __restrict__ Wih2, const float* __restrict__ Whh2,
                      const float* __restrict__ bih2, const float* __restrict__ bhh2,
                      float* __restrict__ out)
{
    const int tid  = threadIdx.x;
    const int grp  = tid >> 6;         // wave index in block = batch element 0..3
    const int l64  = tid & 63;
    const int o    = l64 & 15;         // output unit
    const int half = (l64 >> 4) & 1;   // K-half
    const int s    = l64 >> 5;         // 0: x-side accumulation, 1: h-side accumulation
    const int j0   = half * 8;         // K-chunk base
    const int b    = blockIdx.x * 4 + grp;

    __shared__ float hbuf[4][3][16];   // per-wave per-layer hidden state broadcast

    const float* WihA[3] = {Wih0, Wih1, Wih2};
    const float* WhhA[3] = {Whh0, Whh1, Whh2};
    const float* bihA[3] = {bih0, bih1, bih2};
    const float* bhhA[3] = {bhh0, bhh1, bhh2};

    // Gate weights: this lane's side (x or h), 3 gates x 8 K-elements = 24 VGPRs
    float w0[8], w1[8], w2[8];
    float bias_r[3], bias_z[3], bias_xn[3], bias_hn[3];
    // All weight matrices are [48][16] (ES == HS == 16).
    float wt[3][3][8];
#pragma unroll
    for (int L = 0; L < 3; ++L) {
        const float* Wsel = s ? WhhA[L] : WihA[L];
#pragma unroll
        for (int g = 0; g < 3; ++g) {
            const float4 a0 = *(const float4*)(Wsel + (g * 16 + o) * 16 + j0);
            const float4 a1 = *(const float4*)(Wsel + (g * 16 + o) * 16 + j0 + 4);
            wt[L][g][0] = a0.x; wt[L][g][1] = a0.y; wt[L][g][2] = a0.z; wt[L][g][3] = a0.w;
            wt[L][g][4] = a1.x; wt[L][g][5] = a1.y; wt[L][g][6] = a1.z; wt[L][g][7] = a1.w;
        }
        bias_r[L]  = bihA[L][o]      + bhhA[L][o];
        bias_z[L]  = bihA[L][16 + o] + bhhA[L][16 + o];
        bias_xn[L] = bihA[L][32 + o];
        bias_hn[L] = bhhA[L][32 + o];
    }

    // Embedding weights for this lane's K-chunk (computed in-register, no LDS round trip).
    // W_emb is [16][2]; rows j0..j0+7 -> 16 contiguous floats.
    float wex[8], wey[8], ber[8];
    {
        const float4 e0 = *(const float4*)(W_emb + j0 * 2);
        const float4 e1 = *(const float4*)(W_emb + j0 * 2 + 4);
        const float4 e2 = *(const float4*)(W_emb + j0 * 2 + 8);
        const float4 e3 = *(const float4*)(W_emb + j0 * 2 + 12);
        wex[0] = e0.x; wey[0] = e0.y; wex[1] = e0.z; wey[1] = e0.w;
        wex[2] = e1.x; wey[2] = e1.y; wex[3] = e1.z; wey[3] = e1.w;
        wex[4] = e2.x; wey[4] = e2.y; wex[5] = e2.z; wey[5] = e2.w;
        wex[6] = e3.x; wey[6] = e3.y; wex[7] = e3.z; wey[7] = e3.w;
        const float4 b0 = *(const float4*)(b_emb + j0);
        const float4 b1 = *(const float4*)(b_emb + j0 + 4);
        ber[0] = b0.x; ber[1] = b0.y; ber[2] = b0.z; ber[3] = b0.w;
        ber[4] = b1.x; ber[5] = b1.y; ber[6] = b1.z; ber[7] = b1.w;
    }

    const float wo  = s ? W_out[16 + o] : W_out[o];
    const float bo  = s ? b_out[1] : b_out[0];

    // Initial hidden state
    float hreg[3];
#pragma unroll
    for (int L = 0; L < 3; ++L) hreg[L] = h0[(L * BB + b) * 16 + o];
    if (l64 < 16) {
#pragma unroll
        for (int L = 0; L < 3; ++L) hbuf[grp][L][o] = hreg[L];
    }
    asm volatile("s_waitcnt lgkmcnt(0)" ::: "memory");

    const float* xb   = x + (size_t)b * (TT * 2);
    float*       outb = out + (size_t)b * (TT * 2);
    float2 xc = *(const float2*)(xb);

    for (int t = 0; t < TT; ++t) {
        float2 xnext = make_float2(0.f, 0.f);
        if (t + 1 < TT) xnext = *(const float2*)(xb + (t + 1) * 2);

        // Embedding chunk in registers: e[j] = relu(W_emb[j0+j]·x_t + b_emb[j0+j])
        float e[8];
#pragma unroll
        for (int j = 0; j < 8; ++j)
            e[j] = fmaxf(fmaf(wey[j], xc.y, fmaf(wex[j], xc.x, ber[j])), 0.0f);

#pragma unroll
        for (int L = 0; L < 3; ++L) {
            // s=0 lanes read the layer input (h_{L-1}, this t); s=1 lanes read h_L (prev t).
            // For L==0 the s=0 read is discarded (input comes from in-register e).
            const int Lsel = s ? L : (L > 0 ? L - 1 : 0);
            const float4 v0 = *(const float4*)(&hbuf[grp][Lsel][j0]);
            const float4 v1 = *(const float4*)(&hbuf[grp][Lsel][j0 + 4]);
            float v[8] = {v0.x, v0.y, v0.z, v0.w, v1.x, v1.y, v1.z, v1.w};
            if (L == 0) {
#pragma unroll
                for (int j = 0; j < 8; ++j) v[j] = s ? v[j] : e[j];
            }

            float a0 = 0.f, a1 = 0.f, a2 = 0.f;
#pragma unroll
            for (int j = 0; j < 8; ++j) {
                a0 = fmaf(wt[L][0][j], v[j], a0);
                a1 = fmaf(wt[L][1][j], v[j], a1);
                a2 = fmaf(wt[L][2][j], v[j], a2);
            }
            // Combine K-halves within this side
            a0 += __shfl_xor(a0, 16);
            a1 += __shfl_xor(a1, 16);
            a2 += __shfl_xor(a2, 16);
            // Exchange across sides (x-side <-> h-side)
            const float o0 = __shfl_xor(a0, 32);
            const float o1 = __shfl_xor(a1, 32);
            const float o2 = __shfl_xor(a2, 32);

            const float rsum = a0 + o0 + bias_r[L];
            const float zsum = a1 + o1 + bias_z[L];
            const float xnv  = s ? o2 : a2;   // x-side n pre-activation
            const float hnv  = s ? a2 : o2;   // h-side n pre-activation

            const float r = sigmoid_f(rsum);
            const float z = sigmoid_f(zsum);
            const float n = tanh_f(fmaf(r, hnv + bias_hn[L], xnv + bias_xn[L]));
            const float hnew = fmaf(z, hreg[L] - n, n);   // (1-z)*n + z*h
            hreg[L] = hnew;
            if (l64 < 16) hbuf[grp][L][o] = hnew;
            asm volatile("s_waitcnt lgkmcnt(0)" ::: "memory");
        }

        // Output projection: single xor-tree over o computes p0 (s=0 groups) and p1 (s=1).
        float c = wo * hreg[2];
        c += __shfl_xor(c, 1);
        c += __shfl_xor(c, 2);
        c += __shfl_xor(c, 4);
        c += __shfl_xor(c, 8);
        if ((l64 & 31) == 0) outb[t * 2 + s] = c + bo;

        xc = xnext;
    }

    // Final hidden states appended after out (B*T*2 floats): hidden[L][b][o]
    if (l64 < 16) {
#pragma unroll
        for (int L = 0; L < 3; ++L)
            out[(size_t)BB * TT * 2 + (L * BB + b) * 16 + o] = hreg[L];
    }
}

extern "C" void kernel_launch(void* const* d_in, const int* in_sizes, int n_in,
                              void* d_out, int out_size, void* d_ws, size_t ws_size,
                              hipStream_t stream) {
    const float* x     = (const float*)d_in[0];
    const float* h0    = (const float*)d_in[1];
    const float* W_emb = (const float*)d_in[2];
    const float* b_emb = (const float*)d_in[3];
    const float* W_out = (const float*)d_in[4];
    const float* b_out = (const float*)d_in[5];
    const float* Wih0  = (const float*)d_in[6];
    const float* Whh0  = (const float*)d_in[7];
    const float* bih0  = (const float*)d_in[8];
    const float* bhh0  = (const float*)d_in[9];
    const float* Wih1  = (const float*)d_in[10];
    const float* Whh1  = (const float*)d_in[11];
    const float* bih1  = (const float*)d_in[12];
    const float* bhh1  = (const float*)d_in[13];
    const float* Wih2  = (const float*)d_in[14];
    const float* Whh2  = (const float*)d_in[15];
    const float* bih2  = (const float*)d_in[16];
    const float* bhh2  = (const float*)d_in[17];
    float* out = (float*)d_out;

    gru_fused_kernel<<<dim3(BB / 4), dim3(256), 0, stream>>>(
        x, h0, W_emb, b_emb, W_out, b_out,
        Wih0, Whh0, bih0, bhh0,
        Wih1, Whh1, bih1, bhh1,
        Wih2, Whh2, bih2, bhh2,
        out);
}

// Round 3
// 684.313 us; speedup vs baseline: 1.4124x; 1.4124x over previous
//
#include <hip/hip_runtime.h>

#define TT 512
#define BB 4096

__device__ __forceinline__ float sigmoid_f(float x) {
    return __builtin_amdgcn_rcpf(1.0f + __expf(-x));
}
__device__ __forceinline__ float tanh_f(float x) {
    return fmaf(2.0f, __builtin_amdgcn_rcpf(1.0f + __expf(-2.0f * x)), -1.0f);
}

// DPP row rotate-right by N within each 16-lane row: dst[i] = src[(i-N)&15].
template<int N>
__device__ __forceinline__ float row_ror(float v) {
    return __int_as_float(__builtin_amdgcn_update_dpp(
        0, __float_as_int(v), 0x120 + N, 0xF, 0xF, false));
}

// Lane layout (wave64): lane = o + 16*s + 32*eh
//   o  in 0..15 : output unit (owns h[o] for all layers)
//   s  in 0..1  : x-side / h-side accumulation
//   eh in 0..1  : batch element within wave
// Wave = 2 batch elements; block = 256 thr = 4 waves = 8 elems; grid = 512.
// 2048 waves -> 2 waves/SIMD. No LDS in the t-loop; h lives in registers,
// dot products via DPP row_ror systolic rotation against per-lane permuted weights.
__global__ __launch_bounds__(256, 2)
void gru_rot_kernel(const float* __restrict__ x, const float* __restrict__ h0,
                    const float* __restrict__ W_emb, const float* __restrict__ b_emb,
                    const float* __restrict__ W_out, const float* __restrict__ b_out,
                    const float* __restrict__ Wih0, const float* __restrict__ Whh0,
                    const float* __restrict__ bih0, const float* __restrict__ bhh0,
                    const float* __restrict__ Wih1, const float* __restrict__ Whh1,
                    const float* __restrict__ bih1, const float* __restrict__ bhh1,
                    const float* __restrict__ Wih2, const float* __restrict__ Whh2,
                    const float* __restrict__ bih2, const float* __restrict__ bhh2,
                    float* __restrict__ out)
{
    const int tid = threadIdx.x;
    const int l64 = tid & 63;
    const int o   = l64 & 15;
    const int s   = (l64 >> 4) & 1;
    const int eh  = l64 >> 5;
    const int wv  = tid >> 6;
    const int b   = blockIdx.x * 8 + wv * 2 + eh;

    const float* WihA[3] = {Wih0, Wih1, Wih2};
    const float* WhhA[3] = {Whh0, Whh1, Whh2};
    const float* bihA[3] = {bih0, bih1, bih2};
    const float* bhhA[3] = {bhh0, bhh1, bhh2};

    // Per-lane systolic weights: wt[L][g][k] = W[g*16+o][(o-k)&15], W = this side's matrix.
    // One-time uncoalesced loads (L2-absorbed), 144 VGPRs, all indices compile-time.
    float wt[3][3][16];
#pragma unroll
    for (int L = 0; L < 3; ++L) {
        const float* W = s ? WhhA[L] : WihA[L];
#pragma unroll
        for (int g = 0; g < 3; ++g)
#pragma unroll
            for (int k = 0; k < 16; ++k)
                wt[L][g][k] = W[(g * 16 + o) * 16 + ((o - k) & 15)];
    }
    // Biases folded into accumulator inits: r/z full bias on side 0; n-gate split by side.
    float br[3], bz[3], bn[3];
#pragma unroll
    for (int L = 0; L < 3; ++L) {
        br[L] = s ? 0.0f : bihA[L][o] + bhhA[L][o];
        bz[L] = s ? 0.0f : bihA[L][16 + o] + bhhA[L][16 + o];
        bn[L] = s ? bhhA[L][32 + o] : bihA[L][32 + o];
    }

    const float wex = W_emb[o * 2], wey = W_emb[o * 2 + 1], ber = b_emb[o];
    const float wo  = W_out[s * 16 + o];
    const float bo  = b_out[s];

    float h[3];
#pragma unroll
    for (int L = 0; L < 3; ++L) h[L] = h0[(L * BB + b) * 16 + o];

    const float* xb   = x + (size_t)b * (TT * 2);
    float*       outb = out + (size_t)b * (TT * 2);
    float2 xc = *(const float2*)xb;

    for (int t = 0; t < TT; ++t) {
        float2 xn2 = make_float2(0.f, 0.f);
        if (t + 1 < TT) xn2 = *(const float2*)(xb + (t + 1) * 2);

        // Embedding: each lane computes only its own e[o] (3 ops).
        const float e = fmaxf(fmaf(wey, xc.y, fmaf(wex, xc.x, ber)), 0.0f);

#pragma unroll
        for (int L = 0; L < 3; ++L) {
            // This side's 16-vector input, distributed lane o = v[o].
            float vin;
            if (L == 0) vin = s ? h[0] : e;
            else        vin = s ? h[L] : h[L - 1];

            float a0 = br[L], a1 = bz[L], a2 = bn[L];
            float vr = vin;
            a0 = fmaf(wt[L][0][0], vr, a0);
            a1 = fmaf(wt[L][1][0], vr, a1);
            a2 = fmaf(wt[L][2][0], vr, a2);
#pragma unroll
            for (int k = 1; k < 16; ++k) {
                vr = row_ror<1>(vr);
                a0 = fmaf(wt[L][0][k], vr, a0);
                a1 = fmaf(wt[L][1][k], vr, a1);
                a2 = fmaf(wt[L][2][k], vr, a2);
            }
            // Combine x-side and h-side partial sums (lane ^ 16).
            const float c0 = __shfl_xor(a0, 16);
            const float c1 = __shfl_xor(a1, 16);
            const float c2 = __shfl_xor(a2, 16);
            const float rs  = a0 + c0;
            const float zs  = a1 + c1;
            const float xnv = s ? c2 : a2;   // x-side n pre-activation (incl. bias)
            const float hnv = s ? a2 : c2;   // h-side n pre-activation (incl. bias)

            const float r = sigmoid_f(rs);
            const float z = sigmoid_f(zs);
            const float n = tanh_f(fmaf(r, hnv, xnv));
            h[L] = fmaf(z, h[L] - n, n);     // (1-z)*n + z*h
        }

        // Output: row (eh,s) computes out[b][t][s] = sum_o W_out[s][o]*h2[o] + b_out[s]
        // via 4 ror-add steps (all 16 lanes end with the full sum).
        float p = wo * h[2];
        p += row_ror<1>(p);
        p += row_ror<2>(p);
        p += row_ror<4>(p);
        p += row_ror<8>(p);
        if (o == 0) outb[t * 2 + s] = p + bo;

        xc = xn2;
    }

    // Final hidden states appended after out (B*T*2 floats): hidden[L][b][o]
    if (s == 0) {
#pragma unroll
        for (int L = 0; L < 3; ++L)
            out[(size_t)BB * TT * 2 + (L * BB + b) * 16 + o] = h[L];
    }
}

extern "C" void kernel_launch(void* const* d_in, const int* in_sizes, int n_in,
                              void* d_out, int out_size, void* d_ws, size_t ws_size,
                              hipStream_t stream) {
    const float* x     = (const float*)d_in[0];
    const float* h0    = (const float*)d_in[1];
    const float* W_emb = (const float*)d_in[2];
    const float* b_emb = (const float*)d_in[3];
    const float* W_out = (const float*)d_in[4];
    const float* b_out = (const float*)d_in[5];
    const float* Wih0  = (const float*)d_in[6];
    const float* Whh0  = (const float*)d_in[7];
    const float* bih0  = (const float*)d_in[8];
    const float* bhh0  = (const float*)d_in[9];
    const float* Wih1  = (const float*)d_in[10];
    const float* Whh1  = (const float*)d_in[11];
    const float* bih1  = (const float*)d_in[12];
    const float* bhh1  = (const float*)d_in[13];
    const float* Wih2  = (const float*)d_in[14];
    const float* Whh2  = (const float*)d_in[15];
    const float* bih2  = (const float*)d_in[16];
    const float* bhh2  = (const float*)d_in[17];
    float* out = (float*)d_out;

    gru_rot_kernel<<<dim3(BB / 8), dim3(256), 0, stream>>>(
        x, h0, W_emb, b_emb, W_out, b_out,
        Wih0, Whh0, bih0, bhh0,
        Wih1, Whh1, bih1, bhh1,
        Wih2, Whh2, bih2, bhh2,
        out);
}

// Round 4
// 607.710 us; speedup vs baseline: 1.5904x; 1.1261x over previous
//
#include <hip/hip_runtime.h>
#include <hip/hip_bf16.h>

#define TT 512
#define BB 4096

typedef __attribute__((ext_vector_type(4))) float f32x4;
typedef __attribute__((ext_vector_type(8))) short short8;
typedef __attribute__((ext_vector_type(8))) __bf16 bf16v8;

__device__ __forceinline__ f32x4 MFMA(short8 a, short8 b, f32x4 c) {
    return __builtin_amdgcn_mfma_f32_16x16x32_bf16(
        __builtin_bit_cast(bf16v8, a), __builtin_bit_cast(bf16v8, b), c, 0, 0, 0);
}

__device__ __forceinline__ float sigmoid_f(float x) {
    return __builtin_amdgcn_rcpf(1.0f + __expf(-x));
}
__device__ __forceinline__ float tanh_f(float x) {
    return fmaf(2.0f, __builtin_amdgcn_rcpf(1.0f + __expf(-2.0f * x)), -1.0f);
}

__device__ __forceinline__ ushort bfbits(float f) {
    return __bfloat16_as_ushort(__float2bfloat16(f));
}
__device__ __forceinline__ float bf2f(ushort u) {
    return __uint_as_float(((unsigned)u) << 16);
}

// Split 4 f32 values into pair-duplicated bf16 hi/lo B-fragments:
// B1[2q]=B1[2q+1]=hi(h[q]), B2[2q]=B2[2q+1]=lo(h[q]).
__device__ __forceinline__ void mk_frags(const f32x4& h, short8& B1, short8& B2) {
#pragma unroll
    for (int q = 0; q < 4; ++q) {
        const ushort hi = bfbits(h[q]);
        const ushort lo = bfbits(h[q] - bf2f(hi));
        B1[2 * q] = (short)hi; B1[2 * q + 1] = (short)hi;
        B2[2 * q] = (short)lo; B2[2 * q + 1] = (short)lo;
    }
}

// One wave (64 threads) owns 16 batch columns.
//   n = lane&15 : batch col within tile (also the A-row index m for weight frags)
//   g = lane>>4 : lane group; C/D rows owned = 4g..4g+3; B k-range = 8g..8g+7
// K=32 packing: k = 2c+p, c = 4g+(j>>1) in 0..15 (logical 16-dim), p = j&1 selects
// (hi,lo) on the A side; B duplicates its value across each (2c,2c+1) pair.
// Product of two MFMAs (B=hi-dup, B=lo-dup) = (W_hi+W_lo)@(h_hi+h_lo) exactly.
__global__ __launch_bounds__(64, 1)
void gru_mfma_kernel(const float* __restrict__ x, const float* __restrict__ h0,
                     const float* __restrict__ W_emb, const float* __restrict__ b_emb,
                     const float* __restrict__ W_out, const float* __restrict__ b_out,
                     const float* __restrict__ Wih0, const float* __restrict__ Whh0,
                     const float* __restrict__ bih0, const float* __restrict__ bhh0,
                     const float* __restrict__ Wih1, const float* __restrict__ Whh1,
                     const float* __restrict__ bih1, const float* __restrict__ bhh1,
                     const float* __restrict__ Wih2, const float* __restrict__ Whh2,
                     const float* __restrict__ bih2, const float* __restrict__ bhh2,
                     float* __restrict__ out)
{
    const int l = threadIdx.x & 63;
    const int n = l & 15;          // batch col within the wave's 16-col tile
    const int g = l >> 4;          // lane group
    const int b = blockIdx.x * 16 + n;

    const float* WihA[3] = {Wih0, Wih1, Wih2};
    const float* WhhA[3] = {Whh0, Whh1, Whh2};
    const float* bihA[3] = {bih0, bih1, bih2};
    const float* bhhA[3] = {bhh0, bhh1, bhh2};

    // --- A-fragments: aW[L][side 0=ih,1=hh][gate], j-th bf16 = (j&1 ? Wlo : Whi)[m][4g+(j>>1)]
    // with A row m = l&15.
    short8 aW[3][2][3];
#pragma unroll
    for (int L = 0; L < 3; ++L) {
#pragma unroll
        for (int sd = 0; sd < 2; ++sd) {
            const float* W = sd ? WhhA[L] : WihA[L];
#pragma unroll
            for (int gate = 0; gate < 3; ++gate) {
                short8 f;
#pragma unroll
                for (int q = 0; q < 4; ++q) {
                    const float w = W[(gate * 16 + n) * 16 + (4 * g + q)];
                    const ushort hi = bfbits(w);
                    const ushort lo = bfbits(w - bf2f(hi));
                    f[2 * q] = (short)hi; f[2 * q + 1] = (short)lo;
                }
                aW[L][sd][gate] = f;
            }
        }
    }

    // --- biases in C layout (row m = 4g+j)
    f32x4 bR[3], bZ[3], bNX[3], bNH[3];
#pragma unroll
    for (int L = 0; L < 3; ++L) {
#pragma unroll
        for (int j = 0; j < 4; ++j) {
            const int m = 4 * g + j;
            bR[L][j]  = bihA[L][m]      + bhhA[L][m];
            bZ[L][j]  = bihA[L][16 + m] + bhhA[L][16 + m];
            bNX[L][j] = bihA[L][32 + m];
            bNH[L][j] = bhhA[L][32 + m];
        }
    }

    // --- embedding rows c = 4g+q (B-layout k rows), per-lane x column n
    float wex[4], wey[4], beq[4];
#pragma unroll
    for (int q = 0; q < 4; ++q) {
        const int c = 4 * g + q;
        wex[q] = W_emb[c * 2]; wey[q] = W_emb[c * 2 + 1]; beq[q] = b_emb[c];
    }
    // --- output weights rows m = 4g+j
    float wo0[4], wo1[4];
#pragma unroll
    for (int j = 0; j < 4; ++j) { wo0[j] = W_out[4 * g + j]; wo1[j] = W_out[16 + 4 * g + j]; }
    const float bo0 = b_out[0], bo1 = b_out[1];

    // --- hidden state in C layout + its B-fragments
    f32x4 hC[3]; short8 hB1[3], hB2[3];
#pragma unroll
    for (int L = 0; L < 3; ++L) {
        hC[L] = *(const f32x4*)(h0 + ((size_t)L * BB + b) * 16 + 4 * g);
        mk_frags(hC[L], hB1[L], hB2[L]);
    }

    const float* xb = x + (size_t)b * (TT * 2);
    float2 xc = *(const float2*)xb;

#define LAYER(L, inB1, inB2)                                                    \
    {                                                                           \
        f32x4 ar = bR[L], az = bZ[L], anx = bNX[L], anh = bNH[L];               \
        ar  = MFMA(aW[L][0][0], inB1, ar);                                      \
        ar  = MFMA(aW[L][0][0], inB2, ar);                                      \
        ar  = MFMA(aW[L][1][0], hB1[L], ar);                                    \
        ar  = MFMA(aW[L][1][0], hB2[L], ar);                                    \
        az  = MFMA(aW[L][0][1], inB1, az);                                      \
        az  = MFMA(aW[L][0][1], inB2, az);                                      \
        az  = MFMA(aW[L][1][1], hB1[L], az);                                    \
        az  = MFMA(aW[L][1][1], hB2[L], az);                                    \
        anx = MFMA(aW[L][0][2], inB1, anx);                                     \
        anx = MFMA(aW[L][0][2], inB2, anx);                                     \
        anh = MFMA(aW[L][1][2], hB1[L], anh);                                   \
        anh = MFMA(aW[L][1][2], hB2[L], anh);                                   \
        _Pragma("unroll")                                                       \
        for (int j = 0; j < 4; ++j) {                                           \
            const float r = sigmoid_f(ar[j]);                                   \
            const float z = sigmoid_f(az[j]);                                   \
            const float nn = tanh_f(fmaf(r, anh[j], anx[j]));                   \
            hC[L][j] = fmaf(z, hC[L][j] - nn, nn);                              \
        }                                                                       \
        mk_frags(hC[L], hB1[L], hB2[L]);                                        \
    }

    for (int t = 0; t < TT; ++t) {
        float2 xn2 = make_float2(0.f, 0.f);
        if (t + 1 < TT) xn2 = *(const float2*)(xb + (t + 1) * 2);

        // Embedding in B layout: e[c][n] for this lane's c-rows, own column n.
        f32x4 ev;
#pragma unroll
        for (int q = 0; q < 4; ++q)
            ev[q] = fmaxf(fmaf(wey[q], xc.y, fmaf(wex[q], xc.x, beq[q])), 0.0f);
        short8 eB1, eB2;
        mk_frags(ev, eB1, eB2);

        LAYER(0, eB1, eB2)
        LAYER(1, hB1[0], hB2[0])
        LAYER(2, hB1[1], hB2[1])

        // Output projection: each lane reduces its 4 rows, then across groups.
        float p0 = 0.f, p1 = 0.f;
#pragma unroll
        for (int j = 0; j < 4; ++j) {
            p0 = fmaf(wo0[j], hC[2][j], p0);
            p1 = fmaf(wo1[j], hC[2][j], p1);
        }
        p0 += __shfl_xor(p0, 16); p0 += __shfl_xor(p0, 32);
        p1 += __shfl_xor(p1, 16); p1 += __shfl_xor(p1, 32);
        if (g == 0)
            *(float2*)(out + (size_t)b * (TT * 2) + t * 2) = make_float2(p0 + bo0, p1 + bo1);

        xc = xn2;
    }

    // Final hidden states: hidden[L][b][m], each lane stores its 4 contiguous rows.
#pragma unroll
    for (int L = 0; L < 3; ++L)
        *(f32x4*)(out + (size_t)BB * TT * 2 + ((size_t)L * BB + b) * 16 + 4 * g) = hC[L];

#undef LAYER
}

extern "C" void kernel_launch(void* const* d_in, const int* in_sizes, int n_in,
                              void* d_out, int out_size, void* d_ws, size_t ws_size,
                              hipStream_t stream) {
    const float* x     = (const float*)d_in[0];
    const float* h0    = (const float*)d_in[1];
    const float* W_emb = (const float*)d_in[2];
    const float* b_emb = (const float*)d_in[3];
    const float* W_out = (const float*)d_in[4];
    const float* b_out = (const float*)d_in[5];
    const float* Wih0  = (const float*)d_in[6];
    const float* Whh0  = (const float*)d_in[7];
    const float* bih0  = (const float*)d_in[8];
    const float* bhh0  = (const float*)d_in[9];
    const float* Wih1  = (const float*)d_in[10];
    const float* Whh1  = (const float*)d_in[11];
    const float* bih1  = (const float*)d_in[12];
    const float* bhh1  = (const float*)d_in[13];
    const float* Wih2  = (const float*)d_in[14];
    const float* Whh2  = (const float*)d_in[15];
    const float* bih2  = (const float*)d_in[16];
    const float* bhh2  = (const float*)d_in[17];
    float* out = (float*)d_out;

    gru_mfma_kernel<<<dim3(BB / 16), dim3(64), 0, stream>>>(
        x, h0, W_emb, b_emb, W_out, b_out,
        Wih0, Whh0, bih0, bhh0,
        Wih1, Whh1, bih1, bhh1,
        Wih2, Whh2, bih2, bhh2,
        out);
}

// Round 5
// 480.775 us; speedup vs baseline: 2.0103x; 1.2640x over previous
//
#include <hip/hip_runtime.h>
#include <hip/hip_bf16.h>

#define TT 512
#define BB 4096

typedef __attribute__((ext_vector_type(4))) float f32x4;
typedef __attribute__((ext_vector_type(8))) short short8;
typedef __attribute__((ext_vector_type(8))) __bf16 bf16v8;

__device__ __forceinline__ f32x4 MFMA(short8 a, short8 b, f32x4 c) {
    return __builtin_amdgcn_mfma_f32_16x16x32_bf16(
        __builtin_bit_cast(bf16v8, a), __builtin_bit_cast(bf16v8, b), c, 0, 0, 0);
}

__device__ __forceinline__ float sigmoid_f(float x) {
    return __builtin_amdgcn_rcpf(1.0f + __expf(-x));
}
__device__ __forceinline__ float tanh_f(float x) {
    return fmaf(2.0f, __builtin_amdgcn_rcpf(1.0f + __expf(-2.0f * x)), -1.0f);
}

__device__ __forceinline__ ushort bfbits(float f) {
    return __bfloat16_as_ushort(__float2bfloat16(f));
}
__device__ __forceinline__ float bf2f(ushort u) {
    return __uint_as_float(((unsigned)u) << 16);
}

// B-fragment: pair-duplicated bf16 of 4 f32 values: B[2q]=B[2q+1]=bf16(v[q]).
// Paired against A's interleaved (Whi,Wlo) this yields (Whi+Wlo)*bf16(v):
// weights exact to ~17 mantissa bits, input quantized to bf16.
__device__ __forceinline__ short8 mk_b(const f32x4& v) {
    short8 B;
#pragma unroll
    for (int q = 0; q < 4; ++q) {
        const short hi = (short)bfbits(v[q]);
        B[2 * q] = hi; B[2 * q + 1] = hi;
    }
    return B;
}

// One wave (64 threads) owns 16 batch columns.
//   n = lane&15 : batch col (also A-row index m for weight frags)
//   g = lane>>4 : lane group; C/D rows owned = 4g..4g+3; B k-range = 8g..8g+7
// K=32 packing: k = 2c+p, c = 4g+(j>>1) logical dim, p selects (hi,lo) on A;
// B duplicates bf16(v[c]) across each (2c,2c+1) pair.
__global__ __launch_bounds__(64, 1)
void gru_mfma_kernel(const float* __restrict__ x, const float* __restrict__ h0,
                     const float* __restrict__ W_emb, const float* __restrict__ b_emb,
                     const float* __restrict__ W_out, const float* __restrict__ b_out,
                     const float* __restrict__ Wih0, const float* __restrict__ Whh0,
                     const float* __restrict__ bih0, const float* __restrict__ bhh0,
                     const float* __restrict__ Wih1, const float* __restrict__ Whh1,
                     const float* __restrict__ bih1, const float* __restrict__ bhh1,
                     const float* __restrict__ Wih2, const float* __restrict__ Whh2,
                     const float* __restrict__ bih2, const float* __restrict__ bhh2,
                     float* __restrict__ out)
{
    const int l = threadIdx.x & 63;
    const int n = l & 15;          // batch col within the wave's 16-col tile
    const int g = l >> 4;          // lane group
    const int b = blockIdx.x * 16 + n;

    const float* WihA[3] = {Wih0, Wih1, Wih2};
    const float* WhhA[3] = {Whh0, Whh1, Whh2};
    const float* bihA[3] = {bih0, bih1, bih2};
    const float* bhhA[3] = {bhh0, bhh1, bhh2};

    // A-fragments: aW[L][side 0=ih,1=hh][gate]; j-th bf16 = (j&1 ? Wlo : Whi)[n][4g+(j>>1)]
    short8 aW[3][2][3];
#pragma unroll
    for (int L = 0; L < 3; ++L) {
#pragma unroll
        for (int sd = 0; sd < 2; ++sd) {
            const float* W = sd ? WhhA[L] : WihA[L];
#pragma unroll
            for (int gate = 0; gate < 3; ++gate) {
                short8 f;
#pragma unroll
                for (int q = 0; q < 4; ++q) {
                    const float w = W[(gate * 16 + n) * 16 + (4 * g + q)];
                    const ushort hi = bfbits(w);
                    const ushort lo = bfbits(w - bf2f(hi));
                    f[2 * q] = (short)hi; f[2 * q + 1] = (short)lo;
                }
                aW[L][sd][gate] = f;
            }
        }
    }

    // Biases in C layout (row m = 4g+j)
    f32x4 bR[3], bZ[3], bNX[3], bNH[3];
#pragma unroll
    for (int L = 0; L < 3; ++L) {
#pragma unroll
        for (int j = 0; j < 4; ++j) {
            const int m = 4 * g + j;
            bR[L][j]  = bihA[L][m]      + bhhA[L][m];
            bZ[L][j]  = bihA[L][16 + m] + bhhA[L][16 + m];
            bNX[L][j] = bihA[L][32 + m];
            bNH[L][j] = bhhA[L][32 + m];
        }
    }

    // Embedding rows c = 4g+q (B-layout k rows), per-lane x column n
    float wex[4], wey[4], beq[4];
#pragma unroll
    for (int q = 0; q < 4; ++q) {
        const int c = 4 * g + q;
        wex[q] = W_emb[c * 2]; wey[q] = W_emb[c * 2 + 1]; beq[q] = b_emb[c];
    }
    // Output weights rows m = 4g+j
    float wo0[4], wo1[4];
#pragma unroll
    for (int j = 0; j < 4; ++j) { wo0[j] = W_out[4 * g + j]; wo1[j] = W_out[16 + 4 * g + j]; }
    const float bo0 = b_out[0], bo1 = b_out[1];

    // Hidden state in C layout + bf16 B-fragments
    f32x4 hC[3]; short8 hB[3];
#pragma unroll
    for (int L = 0; L < 3; ++L) {
        hC[L] = *(const f32x4*)(h0 + ((size_t)L * BB + b) * 16 + 4 * g);
        hB[L] = mk_b(hC[L]);
    }

    const float* xb = x + (size_t)b * (TT * 2);
    float2 xc = *(const float2*)xb;

#define LAYER(L, inB)                                                           \
    {                                                                           \
        f32x4 ar, az, anx, anh;                                                 \
        ar  = MFMA(aW[L][0][0], inB,   bR[L]);                                  \
        az  = MFMA(aW[L][0][1], inB,   bZ[L]);                                  \
        anx = MFMA(aW[L][0][2], inB,   bNX[L]);                                 \
        anh = MFMA(aW[L][1][2], hB[L], bNH[L]);                                 \
        ar  = MFMA(aW[L][1][0], hB[L], ar);                                     \
        az  = MFMA(aW[L][1][1], hB[L], az);                                     \
        _Pragma("unroll")                                                       \
        for (int j = 0; j < 4; ++j) {                                           \
            const float r = sigmoid_f(ar[j]);                                   \
            const float z = sigmoid_f(az[j]);                                   \
            const float nn = tanh_f(fmaf(r, anh[j], anx[j]));                   \
            hC[L][j] = fmaf(z, hC[L][j] - nn, nn);                              \
        }                                                                       \
        hB[L] = mk_b(hC[L]);                                                    \
    }

    for (int t = 0; t < TT; ++t) {
        float2 xn2 = make_float2(0.f, 0.f);
        if (t + 1 < TT) xn2 = *(const float2*)(xb + (t + 1) * 2);

        // Embedding in B layout: e[c][n] for this lane's c-rows, own column n.
        f32x4 ev;
#pragma unroll
        for (int q = 0; q < 4; ++q)
            ev[q] = fmaxf(fmaf(wey[q], xc.y, fmaf(wex[q], xc.x, beq[q])), 0.0f);
        const short8 eB = mk_b(ev);

        LAYER(0, eB)
        LAYER(1, hB[0])
        LAYER(2, hB[1])

        // Output projection: each lane reduces its 4 rows, then across groups.
        float p0 = 0.f, p1 = 0.f;
#pragma unroll
        for (int j = 0; j < 4; ++j) {
            p0 = fmaf(wo0[j], hC[2][j], p0);
            p1 = fmaf(wo1[j], hC[2][j], p1);
        }
        p0 += __shfl_xor(p0, 16); p0 += __shfl_xor(p0, 32);
        p1 += __shfl_xor(p1, 16); p1 += __shfl_xor(p1, 32);
        if (g == 0)
            *(float2*)(out + (size_t)b * (TT * 2) + t * 2) = make_float2(p0 + bo0, p1 + bo1);

        xc = xn2;
    }

    // Final hidden states: hidden[L][b][m], each lane stores its 4 contiguous rows.
#pragma unroll
    for (int L = 0; L < 3; ++L)
        *(f32x4*)(out + (size_t)BB * TT * 2 + ((size_t)L * BB + b) * 16 + 4 * g) = hC[L];

#undef LAYER
}

extern "C" void kernel_launch(void* const* d_in, const int* in_sizes, int n_in,
                              void* d_out, int out_size, void* d_ws, size_t ws_size,
                              hipStream_t stream) {
    const float* x     = (const float*)d_in[0];
    const float* h0    = (const float*)d_in[1];
    const float* W_emb = (const float*)d_in[2];
    const float* b_emb = (const float*)d_in[3];
    const float* W_out = (const float*)d_in[4];
    const float* b_out = (const float*)d_in[5];
    const float* Wih0  = (const float*)d_in[6];
    const float* Whh0  = (const float*)d_in[7];
    const float* bih0  = (const float*)d_in[8];
    const float* bhh0  = (const float*)d_in[9];
    const float* Wih1  = (const float*)d_in[10];
    const float* Whh1  = (const float*)d_in[11];
    const float* bih1  = (const float*)d_in[12];
    const float* bhh1  = (const float*)d_in[13];
    const float* Wih2  = (const float*)d_in[14];
    const float* Whh2  = (const float*)d_in[15];
    const float* bih2  = (const float*)d_in[16];
    const float* bhh2  = (const float*)d_in[17];
    float* out = (float*)d_out;

    gru_mfma_kernel<<<dim3(BB / 16), dim3(64), 0, stream>>>(
        x, h0, W_emb, b_emb, W_out, b_out,
        Wih0, Whh0, bih0, bhh0,
        Wih1, Whh1, bih1, bhh1,
        Wih2, Whh2, bih2, bhh2,
        out);
}

// Round 6
// 261.500 us; speedup vs baseline: 3.6960x; 1.8385x over previous
//
#include <hip/hip_runtime.h>
#include <hip/hip_bf16.h>

#define TT 512
#define BB 4096

typedef __attribute__((ext_vector_type(4))) float f32x4;
typedef __attribute__((ext_vector_type(8))) short short8;
typedef __attribute__((ext_vector_type(8))) __bf16 bf16v8;

__device__ __forceinline__ f32x4 MFMA(short8 a, short8 b, f32x4 c) {
    return __builtin_amdgcn_mfma_f32_16x16x32_bf16(
        __builtin_bit_cast(bf16v8, a), __builtin_bit_cast(bf16v8, b), c, 0, 0, 0);
}

__device__ __forceinline__ float sigmoid_f(float x) {
    return __builtin_amdgcn_rcpf(1.0f + __expf(-x));
}
__device__ __forceinline__ float tanh_f(float x) {
    return fmaf(2.0f, __builtin_amdgcn_rcpf(1.0f + __expf(-2.0f * x)), -1.0f);
}

__device__ __forceinline__ ushort bfbits(float f) {
    return __bfloat16_as_ushort(__float2bfloat16(f));
}
__device__ __forceinline__ float bf2f(ushort u) {
    return __uint_as_float(((unsigned)u) << 16);
}

// B-fragment: pair-duplicated bf16 of 4 f32 values. Against A's interleaved
// (Whi,Wlo) this computes (Whi+Wlo)*bf16(v): W exact to ~17 bits, v in bf16.
__device__ __forceinline__ short8 mk_b(const f32x4& v) {
    short8 B;
#pragma unroll
    for (int q = 0; q < 4; ++q) {
        const short hi = (short)bfbits(v[q]);
        B[2 * q] = hi; B[2 * q + 1] = hi;
    }
    return B;
}

// Layer-pipelined GRU: block = 192 threads = 3 waves = 3 layers, one 16-batch tile.
// Wave L processes timestep t = s - L at superstep s; h-fragments hop waves via
// double-buffered LDS (lane-linear, conflict-free). One barrier per superstep.
//   n = lane&15 : batch col (A-row m for weight frags)
//   g = lane>>4 : group; C rows 4g..4g+3; B k-rows 4g..4g+3 (pair-duplicated)
__global__ __launch_bounds__(192, 1)
void gru_pipe_kernel(const float* __restrict__ x, const float* __restrict__ h0,
                     const float* __restrict__ W_emb, const float* __restrict__ b_emb,
                     const float* __restrict__ W_out, const float* __restrict__ b_out,
                     const float* __restrict__ Wih0, const float* __restrict__ Whh0,
                     const float* __restrict__ bih0, const float* __restrict__ bhh0,
                     const float* __restrict__ Wih1, const float* __restrict__ Whh1,
                     const float* __restrict__ bih1, const float* __restrict__ bhh1,
                     const float* __restrict__ Wih2, const float* __restrict__ Whh2,
                     const float* __restrict__ bih2, const float* __restrict__ bhh2,
                     float* __restrict__ out)
{
    const int tid = threadIdx.x;
    const int wid = tid >> 6;      // 0..2 : this wave's layer
    const int l   = tid & 63;
    const int n   = l & 15;
    const int g   = l >> 4;
    const int b   = blockIdx.x * 16 + n;

    __shared__ short8 lbuf[2][2][64];   // [parity][producer wave][lane]

    // This wave's layer parameters
    const float* Wih = wid == 0 ? Wih0 : (wid == 1 ? Wih1 : Wih2);
    const float* Whh = wid == 0 ? Whh0 : (wid == 1 ? Whh1 : Whh2);
    const float* bih = wid == 0 ? bih0 : (wid == 1 ? bih1 : bih2);
    const float* bhh = wid == 0 ? bhh0 : (wid == 1 ? bhh1 : bhh2);

    // A-fragments for this layer: aW[side 0=ih,1=hh][gate];
    // j-th bf16 = (j&1 ? Wlo : Whi)[n][4g+(j>>1)]
    short8 aW[2][3];
#pragma unroll
    for (int sd = 0; sd < 2; ++sd) {
        const float* W = sd ? Whh : Wih;
#pragma unroll
        for (int gate = 0; gate < 3; ++gate) {
            short8 f;
#pragma unroll
            for (int q = 0; q < 4; ++q) {
                const float w = W[(gate * 16 + n) * 16 + (4 * g + q)];
                const ushort hi = bfbits(w);
                const ushort lo = bfbits(w - bf2f(hi));
                f[2 * q] = (short)hi; f[2 * q + 1] = (short)lo;
            }
            aW[sd][gate] = f;
        }
    }

    // Biases in C layout (row m = 4g+j)
    f32x4 bR, bZ, bNX, bNH;
#pragma unroll
    for (int j = 0; j < 4; ++j) {
        const int m = 4 * g + j;
        bR[j]  = bih[m]      + bhh[m];
        bZ[j]  = bih[16 + m] + bhh[16 + m];
        bNX[j] = bih[32 + m];
        bNH[j] = bhh[32 + m];
    }

    // Embedding rows c = 4g+q (wave 0 uses these)
    float wex[4], wey[4], beq[4];
#pragma unroll
    for (int q = 0; q < 4; ++q) {
        const int c = 4 * g + q;
        wex[q] = W_emb[c * 2]; wey[q] = W_emb[c * 2 + 1]; beq[q] = b_emb[c];
    }
    // Output weights rows m = 4g+j (wave 2 uses these)
    float wo0[4], wo1[4];
#pragma unroll
    for (int j = 0; j < 4; ++j) { wo0[j] = W_out[4 * g + j]; wo1[j] = W_out[16 + 4 * g + j]; }
    const float bo0 = b_out[0], bo1 = b_out[1];

    // This wave's hidden state
    f32x4 hC = *(const f32x4*)(h0 + ((size_t)wid * BB + b) * 16 + 4 * g);
    short8 hB = mk_b(hC);

    const float* xb = x + (size_t)b * (TT * 2);
    float2 xc = *(const float2*)xb;

    for (int s = 0; s < TT + 2; ++s) {
        const int t = s - wid;
        if (t >= 0 && t < TT) {
            // Input B-fragment: wave0 computes embedding in-register; others read LDS
            // (issued before the h-side MFMAs so its latency hides under them).
            short8 inB;
            if (wid == 0) {
                f32x4 ev;
#pragma unroll
                for (int q = 0; q < 4; ++q)
                    ev[q] = fmaxf(fmaf(wey[q], xc.y, fmaf(wex[q], xc.x, beq[q])), 0.0f);
                inB = mk_b(ev);
                if (t + 1 < TT) xc = *(const float2*)(xb + (t + 1) * 2);  // prefetch
            } else {
                inB = lbuf[(s - 1) & 1][wid - 1][l];
            }

            // h-side MFMAs first (independent of inB)
            f32x4 ar  = MFMA(aW[1][0], hB, bR);
            f32x4 az  = MFMA(aW[1][1], hB, bZ);
            f32x4 anh = MFMA(aW[1][2], hB, bNH);
            // x-side MFMAs
            f32x4 anx = MFMA(aW[0][2], inB, bNX);
            ar = MFMA(aW[0][0], inB, ar);
            az = MFMA(aW[0][1], inB, az);

#pragma unroll
            for (int j = 0; j < 4; ++j) {
                const float r = sigmoid_f(ar[j]);
                const float z = sigmoid_f(az[j]);
                const float nn = tanh_f(fmaf(r, anh[j], anx[j]));
                hC[j] = fmaf(z, hC[j] - nn, nn);
            }
            hB = mk_b(hC);

            if (wid < 2) {
                lbuf[s & 1][wid][l] = hB;    // hand off to the next layer's wave
            } else {
                float p0 = 0.f, p1 = 0.f;
#pragma unroll
                for (int j = 0; j < 4; ++j) {
                    p0 = fmaf(wo0[j], hC[j], p0);
                    p1 = fmaf(wo1[j], hC[j], p1);
                }
                p0 += __shfl_xor(p0, 16); p0 += __shfl_xor(p0, 32);
                p1 += __shfl_xor(p1, 16); p1 += __shfl_xor(p1, 32);
                if (g == 0)
                    *(float2*)(out + (size_t)b * (TT * 2) + t * 2)
                        = make_float2(p0 + bo0, p1 + bo1);
            }
        }
        __syncthreads();
    }

    // Final hidden state: each wave stores its own layer.
    *(f32x4*)(out + (size_t)BB * TT * 2 + ((size_t)wid * BB + b) * 16 + 4 * g) = hC;
}

extern "C" void kernel_launch(void* const* d_in, const int* in_sizes, int n_in,
                              void* d_out, int out_size, void* d_ws, size_t ws_size,
                              hipStream_t stream) {
    const float* x     = (const float*)d_in[0];
    const float* h0    = (const float*)d_in[1];
    const float* W_emb = (const float*)d_in[2];
    const float* b_emb = (const float*)d_in[3];
    const float* W_out = (const float*)d_in[4];
    const float* b_out = (const float*)d_in[5];
    const float* Wih0  = (const float*)d_in[6];
    const float* Whh0  = (const float*)d_in[7];
    const float* bih0  = (const float*)d_in[8];
    const float* bhh0  = (const float*)d_in[9];
    const float* Wih1  = (const float*)d_in[10];
    const float* Whh1  = (const float*)d_in[11];
    const float* bih1  = (const float*)d_in[12];
    const float* bhh1  = (const float*)d_in[13];
    const float* Wih2  = (const float*)d_in[14];
    const float* Whh2  = (const float*)d_in[15];
    const float* bih2  = (const float*)d_in[16];
    const float* bhh2  = (const float*)d_in[17];
    float* out = (float*)d_out;

    gru_pipe_kernel<<<dim3(BB / 16), dim3(192), 0, stream>>>(
        x, h0, W_emb, b_emb, W_out, b_out,
        Wih0, Whh0, bih0, bhh0,
        Wih1, Whh1, bih1, bhh1,
        Wih2, Whh2, bih2, bhh2,
        out);
}

// Round 7
// 203.892 us; speedup vs baseline: 4.7402x; 1.2825x over previous
//
#include <hip/hip_runtime.h>
#include <hip/hip_bf16.h>

#define TT 512
#define BB 4096

typedef __attribute__((ext_vector_type(4))) float f32x4;
typedef __attribute__((ext_vector_type(8))) short short8;
typedef __attribute__((ext_vector_type(8))) __bf16 bf16v8;

__device__ __forceinline__ f32x4 MFMA(short8 a, short8 b, f32x4 c) {
    return __builtin_amdgcn_mfma_f32_16x16x32_bf16(
        __builtin_bit_cast(bf16v8, a), __builtin_bit_cast(bf16v8, b), c, 0, 0, 0);
}

__device__ __forceinline__ float sigmoid_f(float x) {
    return __builtin_amdgcn_rcpf(1.0f + __expf(-x));
}
__device__ __forceinline__ float tanh_f(float x) {
    return fmaf(2.0f, __builtin_amdgcn_rcpf(1.0f + __expf(-2.0f * x)), -1.0f);
}

__device__ __forceinline__ ushort bfbits(float f) {
    return __bfloat16_as_ushort(__float2bfloat16(f));
}
__device__ __forceinline__ float bf2f(ushort u) {
    return __uint_as_float(((unsigned)u) << 16);
}

// B-fragment: pair-duplicated bf16 of 4 f32 values. Against A's interleaved
// (Whi,Wlo) this computes (Whi+Wlo)*bf16(v): W exact to ~17 bits, v in bf16.
__device__ __forceinline__ short8 mk_b(const f32x4& v) {
    short8 B;
#pragma unroll
    for (int q = 0; q < 4; ++q) {
        const short hi = (short)bfbits(v[q]);
        B[2 * q] = hi; B[2 * q + 1] = hi;
    }
    return B;
}

// Lag-2 layer-pipelined GRU, 2 timesteps per superstep.
// Block = 192 thr = 3 waves = 3 layers, one 16-batch tile; grid = 256.
// Wave L processes t = {2(s-L), 2(s-L)+1} at superstep s; fragments hop waves
// via double-buffered LDS. Barrier = lgkmcnt-only s_barrier (no vmcnt drain:
// x-prefetch and out-stores stay in flight across supersteps).
__global__ __launch_bounds__(192, 1)
void gru_pipe2_kernel(const float* __restrict__ x, const float* __restrict__ h0,
                      const float* __restrict__ W_emb, const float* __restrict__ b_emb,
                      const float* __restrict__ W_out, const float* __restrict__ b_out,
                      const float* __restrict__ Wih0, const float* __restrict__ Whh0,
                      const float* __restrict__ bih0, const float* __restrict__ bhh0,
                      const float* __restrict__ Wih1, const float* __restrict__ Whh1,
                      const float* __restrict__ bih1, const float* __restrict__ bhh1,
                      const float* __restrict__ Wih2, const float* __restrict__ Whh2,
                      const float* __restrict__ bih2, const float* __restrict__ bhh2,
                      float* __restrict__ out)
{
    const int tid = threadIdx.x;
    const int wid = tid >> 6;      // 0..2 : this wave's layer
    const int l   = tid & 63;
    const int n   = l & 15;
    const int g   = l >> 4;
    const int b   = blockIdx.x * 16 + n;

    __shared__ short8 lbuf[2][2][2][64];   // [parity][producer][tslot][lane] = 8 KiB

    const float* Wih = wid == 0 ? Wih0 : (wid == 1 ? Wih1 : Wih2);
    const float* Whh = wid == 0 ? Whh0 : (wid == 1 ? Whh1 : Whh2);
    const float* bih = wid == 0 ? bih0 : (wid == 1 ? bih1 : bih2);
    const float* bhh = wid == 0 ? bhh0 : (wid == 1 ? bhh1 : bhh2);

    // A-fragments: aW[side 0=ih,1=hh][gate]; j-th bf16 = (j&1 ? Wlo : Whi)[n][4g+(j>>1)]
    short8 aW[2][3];
#pragma unroll
    for (int sd = 0; sd < 2; ++sd) {
        const float* W = sd ? Whh : Wih;
#pragma unroll
        for (int gate = 0; gate < 3; ++gate) {
            short8 f;
#pragma unroll
            for (int q = 0; q < 4; ++q) {
                const float w = W[(gate * 16 + n) * 16 + (4 * g + q)];
                const ushort hi = bfbits(w);
                const ushort lo = bfbits(w - bf2f(hi));
                f[2 * q] = (short)hi; f[2 * q + 1] = (short)lo;
            }
            aW[sd][gate] = f;
        }
    }

    // Biases in C layout (row m = 4g+j)
    f32x4 bR, bZ, bNX, bNH;
#pragma unroll
    for (int j = 0; j < 4; ++j) {
        const int m = 4 * g + j;
        bR[j]  = bih[m]      + bhh[m];
        bZ[j]  = bih[16 + m] + bhh[16 + m];
        bNX[j] = bih[32 + m];
        bNH[j] = bhh[32 + m];
    }

    // Embedding rows c = 4g+q (wave 0)
    float wex[4], wey[4], beq[4];
#pragma unroll
    for (int q = 0; q < 4; ++q) {
        const int c = 4 * g + q;
        wex[q] = W_emb[c * 2]; wey[q] = W_emb[c * 2 + 1]; beq[q] = b_emb[c];
    }
    // Output weights rows m = 4g+j (wave 2)
    float wo0[4], wo1[4];
#pragma unroll
    for (int j = 0; j < 4; ++j) { wo0[j] = W_out[4 * g + j]; wo1[j] = W_out[16 + 4 * g + j]; }
    const float bo0 = b_out[0], bo1 = b_out[1];

    f32x4 hC = *(const f32x4*)(h0 + ((size_t)wid * BB + b) * 16 + 4 * g);
    short8 hB = mk_b(hC);

    const float* xb = x + (size_t)b * (TT * 2);
    float4 xcur = make_float4(0.f, 0.f, 0.f, 0.f);
    if (wid == 0) xcur = *(const float4*)xb;     // x[t=0], x[t=1]

    const int NS = TT / 2 + 2;                    // 258 supersteps
    for (int s = 0; s < NS; ++s) {
        const int t0 = 2 * (s - wid);
        if (t0 >= 0 && t0 < TT) {
            short8 inB0, inB1;
            if (wid == 0) {
                f32x4 e0, e1;
#pragma unroll
                for (int q = 0; q < 4; ++q) {
                    e0[q] = fmaxf(fmaf(wey[q], xcur.y, fmaf(wex[q], xcur.x, beq[q])), 0.0f);
                    e1[q] = fmaxf(fmaf(wey[q], xcur.w, fmaf(wex[q], xcur.z, beq[q])), 0.0f);
                }
                inB0 = mk_b(e0); inB1 = mk_b(e1);
                if (t0 + 2 < TT) xcur = *(const float4*)(xb + (t0 + 2) * 2);  // prefetch
            } else {
                inB0 = lbuf[(s - 1) & 1][wid - 1][0][l];
                inB1 = lbuf[(s - 1) & 1][wid - 1][1][l];
            }

            // ---- t0 ----
            f32x4 ar  = MFMA(aW[1][0], hB, bR);
            f32x4 az  = MFMA(aW[1][1], hB, bZ);
            f32x4 anh = MFMA(aW[1][2], hB, bNH);
            f32x4 anx = MFMA(aW[0][2], inB0, bNX);
            ar = MFMA(aW[0][0], inB0, ar);
            az = MFMA(aW[0][1], inB0, az);

            // t1 x-side: independent of t0's gates — fills the MFMA pipe while
            // the VALU runs t0's nonlinearity chain.
            f32x4 ar1  = MFMA(aW[0][0], inB1, bR);
            f32x4 az1  = MFMA(aW[0][1], inB1, bZ);
            f32x4 anx1 = MFMA(aW[0][2], inB1, bNX);

#pragma unroll
            for (int j = 0; j < 4; ++j) {
                const float r = sigmoid_f(ar[j]);
                const float z = sigmoid_f(az[j]);
                const float nn = tanh_f(fmaf(r, anh[j], anx[j]));
                hC[j] = fmaf(z, hC[j] - nn, nn);
            }
            hB = mk_b(hC);
            const short8 hB0 = hB;      // h(t0) fragment for handoff
            const f32x4  hC0 = hC;      // h2(t0) for wave 2's projection

            // ---- t1 ----
            f32x4 anh1 = MFMA(aW[1][2], hB, bNH);
            ar1 = MFMA(aW[1][0], hB, ar1);
            az1 = MFMA(aW[1][1], hB, az1);

#pragma unroll
            for (int j = 0; j < 4; ++j) {
                const float r = sigmoid_f(ar1[j]);
                const float z = sigmoid_f(az1[j]);
                const float nn = tanh_f(fmaf(r, anh1[j], anx1[j]));
                hC[j] = fmaf(z, hC[j] - nn, nn);
            }
            hB = mk_b(hC);

            if (wid < 2) {
                lbuf[s & 1][wid][0][l] = hB0;
                lbuf[s & 1][wid][1][l] = hB;
            } else {
                float p00 = 0.f, p01 = 0.f, p10 = 0.f, p11 = 0.f;
#pragma unroll
                for (int j = 0; j < 4; ++j) {
                    p00 = fmaf(wo0[j], hC0[j], p00);
                    p01 = fmaf(wo1[j], hC0[j], p01);
                    p10 = fmaf(wo0[j], hC[j], p10);
                    p11 = fmaf(wo1[j], hC[j], p11);
                }
                p00 += __shfl_xor(p00, 16); p00 += __shfl_xor(p00, 32);
                p01 += __shfl_xor(p01, 16); p01 += __shfl_xor(p01, 32);
                p10 += __shfl_xor(p10, 16); p10 += __shfl_xor(p10, 32);
                p11 += __shfl_xor(p11, 16); p11 += __shfl_xor(p11, 32);
                if (g == 0)
                    *(float4*)(out + (size_t)b * (TT * 2) + t0 * 2)
                        = make_float4(p00 + bo0, p01 + bo1, p10 + bo0, p11 + bo1);
            }
        }
        // LDS-only barrier: drain ds ops, fence the compiler, s_barrier.
        // Deliberately NOT draining vmcnt/expcnt (x-prefetch + out-stores fly on).
        asm volatile("s_waitcnt lgkmcnt(0)\n\ts_barrier" ::: "memory");
    }

    // Final hidden state: each wave stores its own layer.
    *(f32x4*)(out + (size_t)BB * TT * 2 + ((size_t)wid * BB + b) * 16 + 4 * g) = hC;
}

extern "C" void kernel_launch(void* const* d_in, const int* in_sizes, int n_in,
                              void* d_out, int out_size, void* d_ws, size_t ws_size,
                              hipStream_t stream) {
    const float* x     = (const float*)d_in[0];
    const float* h0    = (const float*)d_in[1];
    const float* W_emb = (const float*)d_in[2];
    const float* b_emb = (const float*)d_in[3];
    const float* W_out = (const float*)d_in[4];
    const float* b_out = (const float*)d_in[5];
    const float* Wih0  = (const float*)d_in[6];
    const float* Whh0  = (const float*)d_in[7];
    const float* bih0  = (const float*)d_in[8];
    const float* bhh0  = (const float*)d_in[9];
    const float* Wih1  = (const float*)d_in[10];
    const float* Whh1  = (const float*)d_in[11];
    const float* bih1  = (const float*)d_in[12];
    const float* bhh1  = (const float*)d_in[13];
    const float* Wih2  = (const float*)d_in[14];
    const float* Whh2  = (const float*)d_in[15];
    const float* bih2  = (const float*)d_in[16];
    const float* bhh2  = (const float*)d_in[17];
    float* out = (float*)d_out;

    gru_pipe2_kernel<<<dim3(BB / 16), dim3(192), 0, stream>>>(
        x, h0, W_emb, b_emb, W_out, b_out,
        Wih0, Whh0, bih0, bhh0,
        Wih1, Whh1, bih1, bhh1,
        Wih2, Whh2, bih2, bhh2,
        out);
}

// Round 8
// 192.276 us; speedup vs baseline: 5.0266x; 1.0604x over previous
//
#include <hip/hip_runtime.h>
#include <hip/hip_bf16.h>

#define TT 512
#define BB 4096

typedef __attribute__((ext_vector_type(4))) float f32x4;
typedef __attribute__((ext_vector_type(8))) short short8;
typedef __attribute__((ext_vector_type(8))) __bf16 bf16v8;

__device__ __forceinline__ f32x4 MFMA(short8 a, short8 b, f32x4 c) {
    return __builtin_amdgcn_mfma_f32_16x16x32_bf16(
        __builtin_bit_cast(bf16v8, a), __builtin_bit_cast(bf16v8, b), c, 0, 0, 0);
}

__device__ __forceinline__ float sigmoid_f(float x) {
    return __builtin_amdgcn_rcpf(1.0f + __expf(-x));
}
__device__ __forceinline__ float tanh_f(float x) {
    return fmaf(2.0f, __builtin_amdgcn_rcpf(1.0f + __expf(-2.0f * x)), -1.0f);
}

__device__ __forceinline__ ushort bfbits(float f) {
    return __bfloat16_as_ushort(__float2bfloat16(f));
}
__device__ __forceinline__ float bf2f(ushort u) {
    return __uint_as_float(((unsigned)u) << 16);
}

// B-fragment: pair-duplicated bf16 of 4 f32 values. Against A's interleaved
// (Whi,Wlo) this computes (Whi+Wlo)*bf16(v): W exact to ~17 bits, v in bf16.
__device__ __forceinline__ short8 mk_b(const f32x4& v) {
    short8 B;
#pragma unroll
    for (int q = 0; q < 4; ++q) {
        const short hi = (short)bfbits(v[q]);
        B[2 * q] = hi; B[2 * q + 1] = hi;
    }
    return B;
}

// Layer-pipelined GRU, 4 timesteps per superstep, 4 waves:
//   wave 0..2 = GRU layers (wave L does t = 4(s-L)..4(s-L)+3 at superstep s)
//   wave 3    = output projection + stores (lag 3), on the otherwise-idle 4th SIMD
// Block = 256 thr, one 16-batch tile; grid = 256. Fragments hop waves via
// double-buffered LDS; barrier is lgkmcnt-only (vm stores/loads fly across).
__global__ __launch_bounds__(256, 1)
void gru_pipe4_kernel(const float* __restrict__ x, const float* __restrict__ h0,
                      const float* __restrict__ W_emb, const float* __restrict__ b_emb,
                      const float* __restrict__ W_out, const float* __restrict__ b_out,
                      const float* __restrict__ Wih0, const float* __restrict__ Whh0,
                      const float* __restrict__ bih0, const float* __restrict__ bhh0,
                      const float* __restrict__ Wih1, const float* __restrict__ Whh1,
                      const float* __restrict__ bih1, const float* __restrict__ bhh1,
                      const float* __restrict__ Wih2, const float* __restrict__ Whh2,
                      const float* __restrict__ bih2, const float* __restrict__ bhh2,
                      float* __restrict__ out)
{
    const int tid = threadIdx.x;
    const int wid = tid >> 6;      // 0..2 layer waves, 3 = projection wave
    const int l   = tid & 63;
    const int n   = l & 15;
    const int g   = l >> 4;
    const int b   = blockIdx.x * 16 + n;

    __shared__ short8 lbuf[2][2][4][64];  // 16 KiB [parity][producer L][tslot][lane]
    __shared__ f32x4  obuf[2][4][64];     //  8 KiB [parity][tslot][lane] : h2(t)

    const int lw = wid < 3 ? wid : 2;     // wave3 borrows layer-2 params (unused)
    const float* Wih = lw == 0 ? Wih0 : (lw == 1 ? Wih1 : Wih2);
    const float* Whh = lw == 0 ? Whh0 : (lw == 1 ? Whh1 : Whh2);
    const float* bih = lw == 0 ? bih0 : (lw == 1 ? bih1 : bih2);
    const float* bhh = lw == 0 ? bhh0 : (lw == 1 ? bhh1 : bhh2);

    // A-fragments: aW[side 0=ih,1=hh][gate]; j-th bf16 = (j&1 ? Wlo : Whi)[n][4g+(j>>1)]
    short8 aW[2][3];
#pragma unroll
    for (int sd = 0; sd < 2; ++sd) {
        const float* W = sd ? Whh : Wih;
#pragma unroll
        for (int gate = 0; gate < 3; ++gate) {
            short8 f;
#pragma unroll
            for (int q = 0; q < 4; ++q) {
                const float w = W[(gate * 16 + n) * 16 + (4 * g + q)];
                const ushort hi = bfbits(w);
                const ushort lo = bfbits(w - bf2f(hi));
                f[2 * q] = (short)hi; f[2 * q + 1] = (short)lo;
            }
            aW[sd][gate] = f;
        }
    }

    // Biases in C layout (row m = 4g+j)
    f32x4 bR, bZ, bNX, bNH;
#pragma unroll
    for (int j = 0; j < 4; ++j) {
        const int m = 4 * g + j;
        bR[j]  = bih[m]      + bhh[m];
        bZ[j]  = bih[16 + m] + bhh[16 + m];
        bNX[j] = bih[32 + m];
        bNH[j] = bhh[32 + m];
    }

    // Embedding rows c = 4g+q (wave 0)
    float wex[4], wey[4], beq[4];
#pragma unroll
    for (int q = 0; q < 4; ++q) {
        const int c = 4 * g + q;
        wex[q] = W_emb[c * 2]; wey[q] = W_emb[c * 2 + 1]; beq[q] = b_emb[c];
    }
    // Output weights rows m = 4g+j (wave 3)
    float wo0[4], wo1[4];
#pragma unroll
    for (int j = 0; j < 4; ++j) { wo0[j] = W_out[4 * g + j]; wo1[j] = W_out[16 + 4 * g + j]; }
    const float bo0 = b_out[0], bo1 = b_out[1];

    f32x4 hC = *(const f32x4*)(h0 + ((size_t)lw * BB + b) * 16 + 4 * g);
    short8 hB = mk_b(hC);

    const float* xb = x + (size_t)b * (TT * 2);
    float4 xc0 = make_float4(0.f, 0.f, 0.f, 0.f), xc1 = xc0;
    if (wid == 0) { xc0 = *(const float4*)xb; xc1 = *(const float4*)(xb + 4); }

#define GATES(AR, AZ, ANH, ANX)                                         \
    do {                                                                \
        _Pragma("unroll")                                               \
        for (int j = 0; j < 4; ++j) {                                   \
            const float r = sigmoid_f(AR[j]);                           \
            const float z = sigmoid_f(AZ[j]);                           \
            const float nn = tanh_f(fmaf(r, ANH[j], ANX[j]));           \
            hC[j] = fmaf(z, hC[j] - nn, nn);                            \
        }                                                               \
        hB = mk_b(hC);                                                  \
    } while (0)

#define HANDOFF(i)                                                      \
    do {                                                                \
        if (wid < 2) lbuf[s & 1][wid][i][l] = hB;                       \
        else         obuf[s & 1][i][l] = hC;                            \
    } while (0)

    const int NS = TT / 4 + 3;   // 131 supersteps
    for (int s = 0; s < NS; ++s) {
        const int t0 = 4 * (s - wid);   // wave3: t0 = 4(s-3) via wid=3
        if (t0 >= 0 && t0 < TT) {
            if (wid < 3) {
                // ---- input fragments for t0..t0+3 ----
                short8 inB0, inB1, inB2, inB3;
                if (wid == 0) {
                    f32x4 e0, e1, e2, e3;
#pragma unroll
                    for (int q = 0; q < 4; ++q) {
                        e0[q] = fmaxf(fmaf(wey[q], xc0.y, fmaf(wex[q], xc0.x, beq[q])), 0.0f);
                        e1[q] = fmaxf(fmaf(wey[q], xc0.w, fmaf(wex[q], xc0.z, beq[q])), 0.0f);
                        e2[q] = fmaxf(fmaf(wey[q], xc1.y, fmaf(wex[q], xc1.x, beq[q])), 0.0f);
                        e3[q] = fmaxf(fmaf(wey[q], xc1.w, fmaf(wex[q], xc1.z, beq[q])), 0.0f);
                    }
                    inB0 = mk_b(e0); inB1 = mk_b(e1); inB2 = mk_b(e2); inB3 = mk_b(e3);
                    if (t0 + 4 < TT) {   // prefetch next superstep's x
                        xc0 = *(const float4*)(xb + (t0 + 4) * 2);
                        xc1 = *(const float4*)(xb + (t0 + 4) * 2 + 4);
                    }
                } else {
                    const int pp = (s - 1) & 1;
                    inB0 = lbuf[pp][wid - 1][0][l];
                    inB1 = lbuf[pp][wid - 1][1][l];
                    inB2 = lbuf[pp][wid - 1][2][l];
                    inB3 = lbuf[pp][wid - 1][3][l];
                }

                // ---- t0 ----
                f32x4 arA  = MFMA(aW[1][0], hB, bR);
                f32x4 azA  = MFMA(aW[1][1], hB, bZ);
                f32x4 anhA = MFMA(aW[1][2], hB, bNH);
                f32x4 anxA = MFMA(aW[0][2], inB0, bNX);
                arA = MFMA(aW[0][0], inB0, arA);
                azA = MFMA(aW[0][1], inB0, azA);
                // pre-issue x-side t1 (fills MFMA pipe during t0's gate VALU)
                f32x4 arB  = MFMA(aW[0][0], inB1, bR);
                f32x4 azB  = MFMA(aW[0][1], inB1, bZ);
                f32x4 anxB = MFMA(aW[0][2], inB1, bNX);
                GATES(arA, azA, anhA, anxA);
                HANDOFF(0);
                // ---- t1 ----
                f32x4 anhB = MFMA(aW[1][2], hB, bNH);
                arB = MFMA(aW[1][0], hB, arB);
                azB = MFMA(aW[1][1], hB, azB);
                // pre-issue x-side t2
                arA  = MFMA(aW[0][0], inB2, bR);
                azA  = MFMA(aW[0][1], inB2, bZ);
                anxA = MFMA(aW[0][2], inB2, bNX);
                GATES(arB, azB, anhB, anxB);
                HANDOFF(1);
                // ---- t2 ----
                anhA = MFMA(aW[1][2], hB, bNH);
                arA = MFMA(aW[1][0], hB, arA);
                azA = MFMA(aW[1][1], hB, azA);
                // pre-issue x-side t3
                arB  = MFMA(aW[0][0], inB3, bR);
                azB  = MFMA(aW[0][1], inB3, bZ);
                anxB = MFMA(aW[0][2], inB3, bNX);
                GATES(arA, azA, anhA, anxA);
                HANDOFF(2);
                // ---- t3 ----
                anhB = MFMA(aW[1][2], hB, bNH);
                arB = MFMA(aW[1][0], hB, arB);
                azB = MFMA(aW[1][1], hB, azB);
                GATES(arB, azB, anhB, anxB);
                HANDOFF(3);
            } else {
                // ---- wave 3: projection + stores for t0..t0+3 (h2 from wave2, s-1) ----
                const int pp = (s - 1) & 1;
                float p[8];
#pragma unroll
                for (int i = 0; i < 4; ++i) {
                    const f32x4 h2 = obuf[pp][i][l];
                    float p0 = 0.f, p1 = 0.f;
#pragma unroll
                    for (int j = 0; j < 4; ++j) {
                        p0 = fmaf(wo0[j], h2[j], p0);
                        p1 = fmaf(wo1[j], h2[j], p1);
                    }
                    p0 += __shfl_xor(p0, 16); p0 += __shfl_xor(p0, 32);
                    p1 += __shfl_xor(p1, 16); p1 += __shfl_xor(p1, 32);
                    p[2 * i] = p0 + bo0; p[2 * i + 1] = p1 + bo1;
                }
                if (g == 0) {
                    float* op = out + (size_t)b * (TT * 2) + t0 * 2;
                    *(float4*)(op)     = make_float4(p[0], p[1], p[2], p[3]);
                    *(float4*)(op + 4) = make_float4(p[4], p[5], p[6], p[7]);
                }
            }
        }
        // LDS-only barrier: drain ds ops, fence compiler, s_barrier.
        // vm loads/stores (x prefetch, out stores) deliberately stay in flight.
        asm volatile("s_waitcnt lgkmcnt(0)\n\ts_barrier" ::: "memory");
    }

    // Final hidden state: layer waves store their own layer.
    if (wid < 3)
        *(f32x4*)(out + (size_t)BB * TT * 2 + ((size_t)wid * BB + b) * 16 + 4 * g) = hC;

#undef GATES
#undef HANDOFF
}

extern "C" void kernel_launch(void* const* d_in, const int* in_sizes, int n_in,
                              void* d_out, int out_size, void* d_ws, size_t ws_size,
                              hipStream_t stream) {
    const float* x     = (const float*)d_in[0];
    const float* h0    = (const float*)d_in[1];
    const float* W_emb = (const float*)d_in[2];
    const float* b_emb = (const float*)d_in[3];
    const float* W_out = (const float*)d_in[4];
    const float* b_out = (const float*)d_in[5];
    const float* Wih0  = (const float*)d_in[6];
    const float* Whh0  = (const float*)d_in[7];
    const float* bih0  = (const float*)d_in[8];
    const float* bhh0  = (const float*)d_in[9];
    const float* Wih1  = (const float*)d_in[10];
    const float* Whh1  = (const float*)d_in[11];
    const float* bih1  = (const float*)d_in[12];
    const float* bhh1  = (const float*)d_in[13];
    const float* Wih2  = (const float*)d_in[14];
    const float* Whh2  = (const float*)d_in[15];
    const float* bih2  = (const float*)d_in[16];
    const float* bhh2  = (const float*)d_in[17];
    float* out = (float*)d_out;

    gru_pipe4_kernel<<<dim3(BB / 16), dim3(256), 0, stream>>>(
        x, h0, W_emb, b_emb, W_out, b_out,
        Wih0, Whh0, bih0, bhh0,
        Wih1, Whh1, bih1, bhh1,
        Wih2, Whh2, bih2, bhh2,
        out);
}